// Round 13
// baseline (196.120 us; speedup 1.0000x reference)
//
#include <hip/hip_runtime.h>
#include <hip/hip_bf16.h>
#include <math.h>

typedef short short8 __attribute__((ext_vector_type(8)));
typedef float f32x4 __attribute__((ext_vector_type(4)));
typedef _Float16 f16x8 __attribute__((ext_vector_type(8)));

#define CC 768
#define NN 1024
#define RR 32768
#define MM 512
#define ZSTRIDE 786432      // C*H*W
#define OUT_ATTN_OFF 25165824
#define SPLIT_SC 2048.0f
#define INV_SC   (1.0f / 2048.0f)

static __device__ __forceinline__ short f2bf(float f) {
    __hip_bfloat16 h = __float2bfloat16(f);
    return *reinterpret_cast<short*>(&h);
}

// fast exp for x in [-2.5, +1e-6], f64 accuracy ~1e-14 rel, branch-free
static __device__ __forceinline__ double fast_exp_neg(double x) {
    const double LOG2E = 1.4426950408889634074;
    const double LN2   = 0.6931471805599453094;
    const double MAGIC = 6755399441055744.0;     // 1.5 * 2^52
    double t = x * LOG2E;
    double c = t + MAGIC;
    double n = c - MAGIC;                         // rint(t)
    int ni = (int)__double2loint(c);
    double g = (t - n) * LN2;
    double r = 2.505210838544172e-08;
    r = fma(r, g, 2.755731922398589e-07);
    r = fma(r, g, 2.7557319223985893e-06);
    r = fma(r, g, 2.48015873015873e-05);
    r = fma(r, g, 1.984126984126984e-04);
    r = fma(r, g, 1.388888888888889e-03);
    r = fma(r, g, 8.333333333333333e-03);
    r = fma(r, g, 4.1666666666666664e-02);
    r = fma(r, g, 1.6666666666666666e-01);
    r = fma(r, g, 0.5);
    r = fma(r, g, 1.0);
    r = fma(r, g, 1.0);
    double sc = __hiloint2double((1023 + ni) << 20, 0);   // 2^n
    return r * sc;
}

static __device__ __forceinline__ double fast_rcp(double x) {
    double r = (double)(1.0f / (float)x);
    r = r * (2.0 - x * r);
    r = r * (2.0 - x * r);
    return r;
}

// ---------------- Kernel A: memory norms + f16 hi/lo split + raw bf16 transpose ----------
__global__ __launch_bounds__(256) void prep_mem_kernel(const float* __restrict__ memory,
                                                       _Float16* __restrict__ mem_h,
                                                       _Float16* __restrict__ mem_L,
                                                       short* __restrict__ memT_bf) {
    int m = blockIdx.x;      // 0..511
    int t = threadIdx.x;
    double ss = 0.0;
    for (int c = t; c < CC; c += 256) {
        float v = memory[m * CC + c];
        ss += (double)v * (double)v;
    }
    #pragma unroll
    for (int off = 32; off > 0; off >>= 1) ss += __shfl_xor(ss, off);
    __shared__ double red[4];
    __shared__ double invs;
    if ((t & 63) == 0) red[t >> 6] = ss;
    __syncthreads();
    if (t == 0) {
        double tot = red[0] + red[1] + red[2] + red[3];
        invs = 1.0 / fmax(sqrt(tot), 1e-12);
    }
    __syncthreads();
    float inv = (float)invs;
    for (int c = t; c < CC; c += 256) {
        float v  = memory[m * CC + c];
        float nv = v * inv;
        _Float16 h = (_Float16)nv;
        float r1 = nv - (float)h;
        mem_h[m * CC + c] = h;
        mem_L[m * CC + c] = (_Float16)(r1 * SPLIT_SC);
        memT_bf[c * MM + m] = f2bf(v);
    }
}

// ---------------- Kernel B: scores GEMM, f16 2-split, 128x128, 8 waves ----------------
// B via global_load_lds (linear dest + inverse-swizzled source); A reg-staged 2-deep.
// T4 counted-vmcnt barrier: prefetch loads survive the barrier.
#define SWZ(row_, k_) ((((row_) << 5) + (k_)) ^ (((row_) & 7) << 3))
__global__ __launch_bounds__(512, 4) void scores_gemm_kernel(const float* __restrict__ z,
                                                             const _Float16* __restrict__ mem_h,
                                                             const _Float16* __restrict__ mem_L,
                                                             float* __restrict__ out_scores,
                                                             double* __restrict__ zinv_ws) {
    __shared__ _Float16 AT[2][2][4096];   // [buf][h/L][swz(row,k)] 32 KB
    __shared__ _Float16 BT[2][2][4096];   // 32 KB, DMA-filled
    __shared__ double ssred[512];

    const int t    = threadIdx.x;
    const int lane = t & 63;
    const int wv   = t >> 6;
    const int lrow = lane & 15;
    const int gk   = lane >> 4;
    const int wr   = wv >> 1, wc = wv & 1;
    const int d = blockIdx.x;                 // 0..1023
    const int colblk = (d >> 3) & 3;
    const int rowblk = (d & 7) | ((d >> 5) << 3);   // 0..255
    const int row0 = rowblk * 128;
    const int b    = row0 >> 10;
    const int n0   = row0 & 1023;
    const int cB0  = colblk * 128;

    const int an  = t & 127;
    const int ak8 = (t >> 7) * 8;
    const float* zA = z + (size_t)b * ZSTRIDE + n0 + an;

    // B DMA source: inverse of SWZ so data lands linearly at BT f16 offset 8*t.
    const int br0 = ((t >> 2) ^ (t >> 4)) & 1;
    const int br  = ((t >> 3) << 1) | br0;
    const int bk8 = (((t & 3) ^ ((((t >> 3) & 1) << 1) | br0)) << 3);
    const _Float16* srcBh = mem_h + (size_t)(cB0 + br) * CC + bk8;
    const _Float16* srcBL = mem_L + (size_t)(cB0 + br) * CC + bk8;

    double ss = 0.0;
    f32x4 am[2][4], ax[2][4];
    #pragma unroll
    for (int fc = 0; fc < 2; ++fc)
        #pragma unroll
        for (int fn = 0; fn < 4; ++fn) {
            am[fc][fn] = (f32x4){0.f, 0.f, 0.f, 0.f};
            ax[fc][fn] = (f32x4){0.f, 0.f, 0.f, 0.f};
        }

    float avX[8], avY[8];

    #define DMA_B(bb_, kt_)                                                    \
        do {                                                                   \
            __builtin_amdgcn_global_load_lds(                                  \
                (const __attribute__((address_space(1))) void*)(srcBh + (kt_) * 32), \
                (__attribute__((address_space(3))) void*)(&BT[bb_][0][wv * 512]),    \
                16, 0, 0);                                                     \
            __builtin_amdgcn_global_load_lds(                                  \
                (const __attribute__((address_space(1))) void*)(srcBL + (kt_) * 32), \
                (__attribute__((address_space(3))) void*)(&BT[bb_][1][wv * 512]),    \
                16, 0, 0);                                                     \
        } while (0)

    #define LOAD_A(kt_, av_)                                                   \
        do {                                                                   \
            _Pragma("unroll")                                                  \
            for (int j = 0; j < 8; ++j)                                        \
                av_[j] = zA[(size_t)((kt_) * 32 + ak8 + j) * NN];              \
        } while (0)

    #define WRITE_A(bb_, av_)                                                  \
        do {                                                                   \
            f16x8 h8, l8;                                                      \
            _Pragma("unroll")                                                  \
            for (int j = 0; j < 8; ++j) {                                      \
                float v = av_[j];                                              \
                ss = fma((double)v, (double)v, ss);                            \
                _Float16 h = (_Float16)v;                                      \
                h8[j] = h;                                                     \
                l8[j] = (_Float16)((v - (float)h) * SPLIT_SC);                 \
            }                                                                  \
            *reinterpret_cast<f16x8*>(&AT[bb_][0][SWZ(an, ak8)]) = h8;         \
            *reinterpret_cast<f16x8*>(&AT[bb_][1][SWZ(an, ak8)]) = l8;         \
        } while (0)

    #define MFMA_BLOCK(cur_)                                                       \
        do {                                                                       \
            f16x8 ah0 = *reinterpret_cast<const f16x8*>(                           \
                &AT[cur_][0][SWZ(wr * 32 + lrow, gk * 8)]);                        \
            f16x8 ah1 = *reinterpret_cast<const f16x8*>(                           \
                &AT[cur_][0][SWZ(wr * 32 + 16 + lrow, gk * 8)]);                   \
            f16x8 aL0 = *reinterpret_cast<const f16x8*>(                           \
                &AT[cur_][1][SWZ(wr * 32 + lrow, gk * 8)]);                        \
            f16x8 aL1 = *reinterpret_cast<const f16x8*>(                           \
                &AT[cur_][1][SWZ(wr * 32 + 16 + lrow, gk * 8)]);                   \
            __builtin_amdgcn_s_setprio(1);                                         \
            _Pragma("unroll")                                                      \
            for (int fn = 0; fn < 4; ++fn) {                                       \
                f16x8 bhf = *reinterpret_cast<const f16x8*>(                       \
                    &BT[cur_][0][SWZ(wc * 64 + fn * 16 + lrow, gk * 8)]);          \
                f16x8 bLf = *reinterpret_cast<const f16x8*>(                       \
                    &BT[cur_][1][SWZ(wc * 64 + fn * 16 + lrow, gk * 8)]);          \
                am[0][fn] = __builtin_amdgcn_mfma_f32_16x16x32_f16(ah0, bhf, am[0][fn], 0, 0, 0); \
                ax[0][fn] = __builtin_amdgcn_mfma_f32_16x16x32_f16(aL0, bhf, ax[0][fn], 0, 0, 0); \
                ax[0][fn] = __builtin_amdgcn_mfma_f32_16x16x32_f16(ah0, bLf, ax[0][fn], 0, 0, 0); \
                am[1][fn] = __builtin_amdgcn_mfma_f32_16x16x32_f16(ah1, bhf, am[1][fn], 0, 0, 0); \
                ax[1][fn] = __builtin_amdgcn_mfma_f32_16x16x32_f16(aL1, bhf, ax[1][fn], 0, 0, 0); \
                ax[1][fn] = __builtin_amdgcn_mfma_f32_16x16x32_f16(ah1, bLf, ax[1][fn], 0, 0, 0); \
            }                                                                      \
            __builtin_amdgcn_s_setprio(0);                                         \
        } while (0)

    // T4 counted barrier: drain own DMA (2 newest-but-oldest vmem) + own ds_writes,
    // leave the 8 A-prefetch loads in flight across the barrier.
    #define PIPE_BARRIER()                                                     \
        do {                                                                   \
            asm volatile("s_waitcnt vmcnt(8) lgkmcnt(0)" ::: "memory");        \
            __builtin_amdgcn_s_barrier();                                      \
            __builtin_amdgcn_sched_barrier(0);                                 \
        } while (0)

    // ---- prologue: tile0 staged; tile1's z in flight across the barrier ----
    DMA_B(0, 0);
    LOAD_A(0, avX);
    LOAD_A(1, avY);
    WRITE_A(0, avX);
    PIPE_BARRIER();

    // ---- main loop: phases 0..21, all shape-identical (counts valid) ----
    #pragma unroll 1
    for (int kt = 0; kt < 22; kt += 2) {
        // even phase: compute buf0 = tile kt
        DMA_B(1, kt + 1);
        LOAD_A(kt + 2, avX);
        MFMA_BLOCK(0);
        WRITE_A(1, avY);
        PIPE_BARRIER();
        // odd phase: compute buf1 = tile kt+1
        DMA_B(0, kt + 2);
        LOAD_A(kt + 3, avY);
        MFMA_BLOCK(1);
        WRITE_A(0, avX);
        PIPE_BARRIER();
    }
    // ---- tail: phase 22 (tile22) + phase 23 (tile23) ----
    DMA_B(1, 23);
    MFMA_BLOCK(0);
    WRITE_A(1, avY);
    __syncthreads();
    MFMA_BLOCK(1);

    #undef DMA_B
    #undef LOAD_A
    #undef WRITE_A
    #undef MFMA_BLOCK
    #undef PIPE_BARRIER

    // ---- store raw scores ----
    #pragma unroll
    for (int fc = 0; fc < 2; ++fc)
        #pragma unroll
        for (int fn = 0; fn < 4; ++fn)
            #pragma unroll
            for (int rg = 0; rg < 4; ++rg) {
                int row = row0 + wr * 32 + fc * 16 + gk * 4 + rg;
                int col = cB0 + wc * 64 + fn * 16 + lrow;
                out_scores[(size_t)row * MM + col] = am[fc][fn][rg] + ax[fc][fn][rg] * INV_SC;
            }

    // ---- z row inverse norms ----
    ssred[t] = ss;
    __syncthreads();
    if (colblk == 0 && t < 128) {
        double tot = ssred[t] + ssred[t + 128] + ssred[t + 256] + ssred[t + 384];
        zinv_ws[row0 + t] = 1.0 / fmax(sqrt(tot), 1e-12);
    }
}
#undef SWZ

// ---------------- Kernel C: in-place softmax + hardshrink + renorm (f64) -------
__global__ __launch_bounds__(256) void epilogue_kernel(float* __restrict__ attn,
                                                       const double* __restrict__ zinv_ws) {
    const int t    = threadIdx.x;
    const int lane = t & 63;
    const int wv   = t >> 6;
    const int row0 = blockIdx.x * 64;

    #pragma unroll 1
    for (int i = 0; i < 16; ++i) {
        int row = row0 + wv * 16 + i;
        double zi = zinv_ws[row];
        float* rp = attn + (size_t)row * MM;
        f32x4 x0 = *reinterpret_cast<const f32x4*>(&rp[lane * 4]);
        f32x4 x1 = *reinterpret_cast<const f32x4*>(&rp[256 + lane * 4]);
        double s0 = (double)x0[0] * zi, s1 = (double)x0[1] * zi;
        double s2 = (double)x0[2] * zi, s3 = (double)x0[3] * zi;
        double s4 = (double)x1[0] * zi, s5 = (double)x1[1] * zi;
        double s6 = (double)x1[2] * zi, s7 = (double)x1[3] * zi;
        double mx = fmax(fmax(fmax(s0, s1), fmax(s2, s3)),
                         fmax(fmax(s4, s5), fmax(s6, s7)));
        #pragma unroll
        for (int off = 32; off > 0; off >>= 1) mx = fmax(mx, __shfl_xor(mx, off));
        double p0 = fast_exp_neg(s0 - mx), p1 = fast_exp_neg(s1 - mx);
        double p2 = fast_exp_neg(s2 - mx), p3 = fast_exp_neg(s3 - mx);
        double p4 = fast_exp_neg(s4 - mx), p5 = fast_exp_neg(s5 - mx);
        double p6 = fast_exp_neg(s6 - mx), p7 = fast_exp_neg(s7 - mx);
        double Z = ((p0 + p1) + (p2 + p3)) + ((p4 + p5) + (p6 + p7));
        #pragma unroll
        for (int off = 32; off > 0; off >>= 1) Z += __shfl_xor(Z, off);
        double iZ = fast_rcp(Z);
        const double LAM = 1.0 / 512.0;
        double w0 = p0 * iZ, w1 = p1 * iZ, w2 = p2 * iZ, w3 = p3 * iZ;
        double w4 = p4 * iZ, w5 = p5 * iZ, w6 = p6 * iZ, w7 = p7 * iZ;
        double d0 = w0 - LAM, d1 = w1 - LAM, d2 = w2 - LAM, d3 = w3 - LAM;
        double d4 = w4 - LAM, d5 = w5 - LAM, d6 = w6 - LAM, d7 = w7 - LAM;
        double e0 = (d0 > 0.0 ? d0 : 0.0) * w0 * fast_rcp(fabs(d0) + 1e-8);
        double e1 = (d1 > 0.0 ? d1 : 0.0) * w1 * fast_rcp(fabs(d1) + 1e-8);
        double e2 = (d2 > 0.0 ? d2 : 0.0) * w2 * fast_rcp(fabs(d2) + 1e-8);
        double e3 = (d3 > 0.0 ? d3 : 0.0) * w3 * fast_rcp(fabs(d3) + 1e-8);
        double e4 = (d4 > 0.0 ? d4 : 0.0) * w4 * fast_rcp(fabs(d4) + 1e-8);
        double e5 = (d5 > 0.0 ? d5 : 0.0) * w5 * fast_rcp(fabs(d5) + 1e-8);
        double e6 = (d6 > 0.0 ? d6 : 0.0) * w6 * fast_rcp(fabs(d6) + 1e-8);
        double e7 = (d7 > 0.0 ? d7 : 0.0) * w7 * fast_rcp(fabs(d7) + 1e-8);
        double S = ((e0 + e1) + (e2 + e3)) + ((e4 + e5) + (e6 + e7));
        #pragma unroll
        for (int off = 32; off > 0; off >>= 1) S += __shfl_xor(S, off);
        double rinv = fast_rcp(S + 1e-8);
        f32x4 o0 = { (float)(e0 * rinv), (float)(e1 * rinv),
                     (float)(e2 * rinv), (float)(e3 * rinv) };
        f32x4 o1 = { (float)(e4 * rinv), (float)(e5 * rinv),
                     (float)(e6 * rinv), (float)(e7 * rinv) };
        *reinterpret_cast<f32x4*>(&rp[lane * 4])       = o0;
        *reinterpret_cast<f32x4*>(&rp[256 + lane * 4]) = o1;
    }
}

// ---------------- Kernel D: z_hat = attn @ memory via bf16 MFMA, 128x128 tiles ----------
__global__ __launch_bounds__(256, 3) void readout_kernel(const short* __restrict__ memT_bf,
                                                         const float* __restrict__ attn,
                                                         float* __restrict__ out) {
    __shared__ short At[128][40];   // 128 c-rows x 32 m, padded
    __shared__ short Bt[128][40];   // 128 n-rows x 32 m
    const int t = threadIdx.x;
    const int d  = blockIdx.x;              // 0..1535
    const int xs = d & 7;
    const int hi = d >> 3;                  // 0..191
    const int c0idx  = hi % 6;
    const int rowmid = hi / 6;              // 0..31
    const int rb     = xs | (rowmid << 3);  // 0..255
    const int c0     = c0idx * 128;
    const int rowblk = rb * 128;
    const int b  = rowblk >> 10;
    const int nb = rowblk & 1023;
    const int lane = t & 63, wv = t >> 6;
    const int wcr = wv >> 1, wcc = wv & 1;
    const int lrow = lane & 15, gk = lane >> 4;

    f32x4 acc[4][4];
    #pragma unroll
    for (int fc = 0; fc < 4; ++fc)
        #pragma unroll
        for (int fn = 0; fn < 4; ++fn) acc[fc][fn] = (f32x4){0.f, 0.f, 0.f, 0.f};

    const int sr = t >> 1;           // staging row 0..127
    const int ko = (t & 1) * 16;     // m-chunk

    for (int m0 = 0; m0 < MM; m0 += 32) {
        __syncthreads();
        {   // stage A: 128 x 32 bf16 (memT)
            const short8* src = reinterpret_cast<const short8*>(
                &memT_bf[(c0 + sr) * MM + m0 + ko]);
            *reinterpret_cast<short8*>(&At[sr][ko])     = src[0];
            *reinterpret_cast<short8*>(&At[sr][ko + 8]) = src[1];
        }
        {   // stage B: 128 x 32, attn f32 -> bf16, vectorized
            const f32x4* src = reinterpret_cast<const f32x4*>(
                &attn[(size_t)(rowblk + sr) * MM + m0 + ko]);
            f32x4 v0 = src[0], v1 = src[1], v2 = src[2], v3 = src[3];
            short8 s0 = { f2bf(v0[0]), f2bf(v0[1]), f2bf(v0[2]), f2bf(v0[3]),
                          f2bf(v1[0]), f2bf(v1[1]), f2bf(v1[2]), f2bf(v1[3]) };
            short8 s1 = { f2bf(v2[0]), f2bf(v2[1]), f2bf(v2[2]), f2bf(v2[3]),
                          f2bf(v3[0]), f2bf(v3[1]), f2bf(v3[2]), f2bf(v3[3]) };
            *reinterpret_cast<short8*>(&Bt[sr][ko])     = s0;
            *reinterpret_cast<short8*>(&Bt[sr][ko + 8]) = s1;
        }
        __syncthreads();
        short8 af[4], bf[4];
        #pragma unroll
        for (int fc = 0; fc < 4; ++fc)
            af[fc] = *reinterpret_cast<const short8*>(&At[wcr * 64 + fc * 16 + lrow][gk * 8]);
        #pragma unroll
        for (int fn = 0; fn < 4; ++fn)
            bf[fn] = *reinterpret_cast<const short8*>(&Bt[wcc * 64 + fn * 16 + lrow][gk * 8]);
        #pragma unroll
        for (int fc = 0; fc < 4; ++fc)
            #pragma unroll
            for (int fn = 0; fn < 4; ++fn)
                acc[fc][fn] = __builtin_amdgcn_mfma_f32_16x16x32_bf16(af[fc], bf[fn], acc[fc][fn], 0, 0, 0);
    }

    #pragma unroll
    for (int fc = 0; fc < 4; ++fc)
        #pragma unroll
        for (int fn = 0; fn < 4; ++fn)
            #pragma unroll
            for (int reg = 0; reg < 4; ++reg) {
                int c = c0 + wcr * 64 + fc * 16 + gk * 4 + reg;
                int n = nb + wcc * 64 + fn * 16 + lrow;
                out[(size_t)b * ZSTRIDE + (size_t)c * NN + n] = acc[fc][fn][reg];
            }
}

extern "C" void kernel_launch(void* const* d_in, const int* in_sizes, int n_in,
                              void* d_out, int out_size, void* d_ws, size_t ws_size,
                              hipStream_t stream) {
    const float* z      = (const float*)d_in[0];
    const float* memory = (const float*)d_in[1];
    float* out      = (float*)d_out;
    float* out_attn = out + OUT_ATTN_OFF;

    char* wsb = (char*)d_ws;
    _Float16* mem_h   = (_Float16*)wsb;               // 786432 B
    _Float16* mem_L   = (_Float16*)(wsb + 786432);    // 786432 B
    short*    memT_bf = (short*)(wsb + 1572864);      // 786432 B
    double*   zinv_ws = (double*)(wsb + 2359296);     // 262144 B

    prep_mem_kernel<<<512, 256, 0, stream>>>(memory, mem_h, mem_L, memT_bf);
    scores_gemm_kernel<<<1024, 512, 0, stream>>>(z, mem_h, mem_L, out_attn, zinv_ws);
    epilogue_kernel<<<RR / 64, 256, 0, stream>>>(out_attn, zinv_ws);
    readout_kernel<<<1536, 256, 0, stream>>>(memT_bf, out_attn, out);
}

// Round 15
// 190.614 us; speedup vs baseline: 1.0289x; 1.0289x over previous
//
#include <hip/hip_runtime.h>
#include <hip/hip_bf16.h>
#include <math.h>

typedef short short8 __attribute__((ext_vector_type(8)));
typedef float f32x4 __attribute__((ext_vector_type(4)));
typedef _Float16 f16x8 __attribute__((ext_vector_type(8)));

#define CC 768
#define NN 1024
#define RR 32768
#define MM 512
#define ZSTRIDE 786432      // C*H*W
#define OUT_ATTN_OFF 25165824
#define SPLIT_SC 2048.0f
#define INV_SC   (1.0f / 2048.0f)

static __device__ __forceinline__ short f2bf(float f) {
    __hip_bfloat16 h = __float2bfloat16(f);
    return *reinterpret_cast<short*>(&h);
}

// fast exp for x in [-2.5, +1e-6], f64 accuracy ~1e-14 rel, branch-free
static __device__ __forceinline__ double fast_exp_neg(double x) {
    const double LOG2E = 1.4426950408889634074;
    const double LN2   = 0.6931471805599453094;
    const double MAGIC = 6755399441055744.0;     // 1.5 * 2^52
    double t = x * LOG2E;
    double c = t + MAGIC;
    double n = c - MAGIC;                         // rint(t)
    int ni = (int)__double2loint(c);
    double g = (t - n) * LN2;
    double r = 2.505210838544172e-08;
    r = fma(r, g, 2.755731922398589e-07);
    r = fma(r, g, 2.7557319223985893e-06);
    r = fma(r, g, 2.48015873015873e-05);
    r = fma(r, g, 1.984126984126984e-04);
    r = fma(r, g, 1.388888888888889e-03);
    r = fma(r, g, 8.333333333333333e-03);
    r = fma(r, g, 4.1666666666666664e-02);
    r = fma(r, g, 1.6666666666666666e-01);
    r = fma(r, g, 0.5);
    r = fma(r, g, 1.0);
    r = fma(r, g, 1.0);
    double sc = __hiloint2double((1023 + ni) << 20, 0);   // 2^n
    return r * sc;
}

static __device__ __forceinline__ double fast_rcp(double x) {
    double r = (double)(1.0f / (float)x);
    r = r * (2.0 - x * r);
    r = r * (2.0 - x * r);
    return r;
}

// ---------------- Kernel A: memory norms + f16 hi/lo split + raw bf16 transpose ----------
__global__ __launch_bounds__(256) void prep_mem_kernel(const float* __restrict__ memory,
                                                       _Float16* __restrict__ mem_h,
                                                       _Float16* __restrict__ mem_L,
                                                       short* __restrict__ memT_bf) {
    int m = blockIdx.x;      // 0..511
    int t = threadIdx.x;
    double ss = 0.0;
    for (int c = t; c < CC; c += 256) {
        float v = memory[m * CC + c];
        ss += (double)v * (double)v;
    }
    #pragma unroll
    for (int off = 32; off > 0; off >>= 1) ss += __shfl_xor(ss, off);
    __shared__ double red[4];
    __shared__ double invs;
    if ((t & 63) == 0) red[t >> 6] = ss;
    __syncthreads();
    if (t == 0) {
        double tot = red[0] + red[1] + red[2] + red[3];
        invs = 1.0 / fmax(sqrt(tot), 1e-12);
    }
    __syncthreads();
    float inv = (float)invs;
    for (int c = t; c < CC; c += 256) {
        float v  = memory[m * CC + c];
        float nv = v * inv;
        _Float16 h = (_Float16)nv;
        float r1 = nv - (float)h;
        mem_h[m * CC + c] = h;
        mem_L[m * CC + c] = (_Float16)(r1 * SPLIT_SC);
        memT_bf[c * MM + m] = f2bf(v);
    }
}

// ---------------- Kernel B: scores GEMM (r12-exact, best measured) ----------------
#define SWZ(row_, k_) ((((row_) << 5) + (k_)) ^ (((row_) & 7) << 3))
__global__ __launch_bounds__(512, 4) void scores_gemm_kernel(const float* __restrict__ z,
                                                             const _Float16* __restrict__ mem_h,
                                                             const _Float16* __restrict__ mem_L,
                                                             float* __restrict__ out_scores,
                                                             double* __restrict__ zinv_ws) {
    __shared__ _Float16 AT[2][2][4096];   // [buf][h/L][swz(row,k)] 32 KB
    __shared__ _Float16 BT[2][2][4096];   // 32 KB, DMA-filled
    __shared__ double ssred[512];

    const int t    = threadIdx.x;
    const int lane = t & 63;
    const int wv   = t >> 6;
    const int lrow = lane & 15;
    const int gk   = lane >> 4;
    const int wr   = wv >> 1, wc = wv & 1;
    const int d = blockIdx.x;                 // 0..1023
    const int colblk = (d >> 3) & 3;
    const int rowblk = (d & 7) | ((d >> 5) << 3);   // 0..255
    const int row0 = rowblk * 128;
    const int b    = row0 >> 10;
    const int n0   = row0 & 1023;
    const int cB0  = colblk * 128;

    const int an  = t & 127;
    const int ak8 = (t >> 7) * 8;
    const float* zA = z + (size_t)b * ZSTRIDE + n0 + an;

    // B DMA source: inverse of SWZ so data lands linearly at BT f16 offset 8*t.
    const int br0 = ((t >> 2) ^ (t >> 4)) & 1;
    const int br  = ((t >> 3) << 1) | br0;
    const int bk8 = (((t & 3) ^ ((((t >> 3) & 1) << 1) | br0)) << 3);
    const _Float16* srcBh = mem_h + (size_t)(cB0 + br) * CC + bk8;
    const _Float16* srcBL = mem_L + (size_t)(cB0 + br) * CC + bk8;

    double ss = 0.0;
    f32x4 am[2][4], ax[2][4];
    #pragma unroll
    for (int fc = 0; fc < 2; ++fc)
        #pragma unroll
        for (int fn = 0; fn < 4; ++fn) {
            am[fc][fn] = (f32x4){0.f, 0.f, 0.f, 0.f};
            ax[fc][fn] = (f32x4){0.f, 0.f, 0.f, 0.f};
        }

    float avX[8], avY[8];

    #define DMA_B(bb_, kt_)                                                    \
        do {                                                                   \
            __builtin_amdgcn_global_load_lds(                                  \
                (const __attribute__((address_space(1))) void*)(srcBh + (kt_) * 32), \
                (__attribute__((address_space(3))) void*)(&BT[bb_][0][wv * 512]),    \
                16, 0, 0);                                                     \
            __builtin_amdgcn_global_load_lds(                                  \
                (const __attribute__((address_space(1))) void*)(srcBL + (kt_) * 32), \
                (__attribute__((address_space(3))) void*)(&BT[bb_][1][wv * 512]),    \
                16, 0, 0);                                                     \
        } while (0)

    #define LOAD_A(kt_, av_)                                                   \
        do {                                                                   \
            _Pragma("unroll")                                                  \
            for (int j = 0; j < 8; ++j)                                        \
                av_[j] = zA[(size_t)((kt_) * 32 + ak8 + j) * NN];              \
        } while (0)

    #define WRITE_A(bb_, av_)                                                  \
        do {                                                                   \
            f16x8 h8, l8;                                                      \
            _Pragma("unroll")                                                  \
            for (int j = 0; j < 8; ++j) {                                      \
                float v = av_[j];                                              \
                ss = fma((double)v, (double)v, ss);                            \
                _Float16 h = (_Float16)v;                                      \
                h8[j] = h;                                                     \
                l8[j] = (_Float16)((v - (float)h) * SPLIT_SC);                 \
            }                                                                  \
            *reinterpret_cast<f16x8*>(&AT[bb_][0][SWZ(an, ak8)]) = h8;         \
            *reinterpret_cast<f16x8*>(&AT[bb_][1][SWZ(an, ak8)]) = l8;         \
        } while (0)

    #define MFMA_BLOCK(cur_)                                                       \
        do {                                                                       \
            f16x8 ah0 = *reinterpret_cast<const f16x8*>(                           \
                &AT[cur_][0][SWZ(wr * 32 + lrow, gk * 8)]);                        \
            f16x8 ah1 = *reinterpret_cast<const f16x8*>(                           \
                &AT[cur_][0][SWZ(wr * 32 + 16 + lrow, gk * 8)]);                   \
            f16x8 aL0 = *reinterpret_cast<const f16x8*>(                           \
                &AT[cur_][1][SWZ(wr * 32 + lrow, gk * 8)]);                        \
            f16x8 aL1 = *reinterpret_cast<const f16x8*>(                           \
                &AT[cur_][1][SWZ(wr * 32 + 16 + lrow, gk * 8)]);                   \
            _Pragma("unroll")                                                      \
            for (int fn = 0; fn < 4; ++fn) {                                       \
                f16x8 bhf = *reinterpret_cast<const f16x8*>(                       \
                    &BT[cur_][0][SWZ(wc * 64 + fn * 16 + lrow, gk * 8)]);          \
                f16x8 bLf = *reinterpret_cast<const f16x8*>(                       \
                    &BT[cur_][1][SWZ(wc * 64 + fn * 16 + lrow, gk * 8)]);          \
                am[0][fn] = __builtin_amdgcn_mfma_f32_16x16x32_f16(ah0, bhf, am[0][fn], 0, 0, 0); \
                ax[0][fn] = __builtin_amdgcn_mfma_f32_16x16x32_f16(aL0, bhf, ax[0][fn], 0, 0, 0); \
                ax[0][fn] = __builtin_amdgcn_mfma_f32_16x16x32_f16(ah0, bLf, ax[0][fn], 0, 0, 0); \
                am[1][fn] = __builtin_amdgcn_mfma_f32_16x16x32_f16(ah1, bhf, am[1][fn], 0, 0, 0); \
                ax[1][fn] = __builtin_amdgcn_mfma_f32_16x16x32_f16(aL1, bhf, ax[1][fn], 0, 0, 0); \
                ax[1][fn] = __builtin_amdgcn_mfma_f32_16x16x32_f16(ah1, bLf, ax[1][fn], 0, 0, 0); \
            }                                                                      \
        } while (0)

    // ---- prologue: tile0 staged; tile1's z in flight ----
    DMA_B(0, 0);
    LOAD_A(0, avX);
    WRITE_A(0, avX);
    LOAD_A(1, avY);
    __syncthreads();

    #pragma unroll 1
    for (int kt = 0; kt < 24; kt += 2) {
        // even phase: compute buf0 = tile kt
        if (kt + 1 < 24) DMA_B(1, kt + 1);
        if (kt + 2 < 24) LOAD_A(kt + 2, avX);       // 2-deep z prefetch
        MFMA_BLOCK(0);
        if (kt + 1 < 24) WRITE_A(1, avY);
        __syncthreads();
        // odd phase: compute buf1 = tile kt+1
        if (kt + 2 < 24) DMA_B(0, kt + 2);
        if (kt + 3 < 24) LOAD_A(kt + 3, avY);
        MFMA_BLOCK(1);
        if (kt + 2 < 24) WRITE_A(0, avX);
        __syncthreads();
    }
    #undef DMA_B
    #undef LOAD_A
    #undef WRITE_A
    #undef MFMA_BLOCK

    // ---- store raw scores ----
    #pragma unroll
    for (int fc = 0; fc < 2; ++fc)
        #pragma unroll
        for (int fn = 0; fn < 4; ++fn)
            #pragma unroll
            for (int rg = 0; rg < 4; ++rg) {
                int row = row0 + wr * 32 + fc * 16 + gk * 4 + rg;
                int col = cB0 + wc * 64 + fn * 16 + lrow;
                out_scores[(size_t)row * MM + col] = am[fc][fn][rg] + ax[fc][fn][rg] * INV_SC;
            }

    // ---- z row inverse norms ----
    ssred[t] = ss;
    __syncthreads();
    if (colblk == 0 && t < 128) {
        double tot = ssred[t] + ssred[t + 128] + ssred[t + 256] + ssred[t + 384];
        zinv_ws[row0 + t] = 1.0 / fmax(sqrt(tot), 1e-12);
    }
}

// ---------------- Kernel C: in-place softmax + hardshrink + renorm (f64) -------
__global__ __launch_bounds__(256) void epilogue_kernel(float* __restrict__ attn,
                                                       const double* __restrict__ zinv_ws) {
    const int t    = threadIdx.x;
    const int lane = t & 63;
    const int wv   = t >> 6;
    const int row0 = blockIdx.x * 64;

    #pragma unroll 1
    for (int i = 0; i < 16; ++i) {
        int row = row0 + wv * 16 + i;
        double zi = zinv_ws[row];
        float* rp = attn + (size_t)row * MM;
        f32x4 x0 = *reinterpret_cast<const f32x4*>(&rp[lane * 4]);
        f32x4 x1 = *reinterpret_cast<const f32x4*>(&rp[256 + lane * 4]);
        double s0 = (double)x0[0] * zi, s1 = (double)x0[1] * zi;
        double s2 = (double)x0[2] * zi, s3 = (double)x0[3] * zi;
        double s4 = (double)x1[0] * zi, s5 = (double)x1[1] * zi;
        double s6 = (double)x1[2] * zi, s7 = (double)x1[3] * zi;
        double mx = fmax(fmax(fmax(s0, s1), fmax(s2, s3)),
                         fmax(fmax(s4, s5), fmax(s6, s7)));
        #pragma unroll
        for (int off = 32; off > 0; off >>= 1) mx = fmax(mx, __shfl_xor(mx, off));
        double p0 = fast_exp_neg(s0 - mx), p1 = fast_exp_neg(s1 - mx);
        double p2 = fast_exp_neg(s2 - mx), p3 = fast_exp_neg(s3 - mx);
        double p4 = fast_exp_neg(s4 - mx), p5 = fast_exp_neg(s5 - mx);
        double p6 = fast_exp_neg(s6 - mx), p7 = fast_exp_neg(s7 - mx);
        double Z = ((p0 + p1) + (p2 + p3)) + ((p4 + p5) + (p6 + p7));
        #pragma unroll
        for (int off = 32; off > 0; off >>= 1) Z += __shfl_xor(Z, off);
        double iZ = fast_rcp(Z);
        const double LAM = 1.0 / 512.0;
        double w0 = p0 * iZ, w1 = p1 * iZ, w2 = p2 * iZ, w3 = p3 * iZ;
        double w4 = p4 * iZ, w5 = p5 * iZ, w6 = p6 * iZ, w7 = p7 * iZ;
        double d0 = w0 - LAM, d1 = w1 - LAM, d2 = w2 - LAM, d3 = w3 - LAM;
        double d4 = w4 - LAM, d5 = w5 - LAM, d6 = w6 - LAM, d7 = w7 - LAM;
        double e0 = (d0 > 0.0 ? d0 : 0.0) * w0 * fast_rcp(fabs(d0) + 1e-8);
        double e1 = (d1 > 0.0 ? d1 : 0.0) * w1 * fast_rcp(fabs(d1) + 1e-8);
        double e2 = (d2 > 0.0 ? d2 : 0.0) * w2 * fast_rcp(fabs(d2) + 1e-8);
        double e3 = (d3 > 0.0 ? d3 : 0.0) * w3 * fast_rcp(fabs(d3) + 1e-8);
        double e4 = (d4 > 0.0 ? d4 : 0.0) * w4 * fast_rcp(fabs(d4) + 1e-8);
        double e5 = (d5 > 0.0 ? d5 : 0.0) * w5 * fast_rcp(fabs(d5) + 1e-8);
        double e6 = (d6 > 0.0 ? d6 : 0.0) * w6 * fast_rcp(fabs(d6) + 1e-8);
        double e7 = (d7 > 0.0 ? d7 : 0.0) * w7 * fast_rcp(fabs(d7) + 1e-8);
        double S = ((e0 + e1) + (e2 + e3)) + ((e4 + e5) + (e6 + e7));
        #pragma unroll
        for (int off = 32; off > 0; off >>= 1) S += __shfl_xor(S, off);
        double rinv = fast_rcp(S + 1e-8);
        f32x4 o0 = { (float)(e0 * rinv), (float)(e1 * rinv),
                     (float)(e2 * rinv), (float)(e3 * rinv) };
        f32x4 o1 = { (float)(e4 * rinv), (float)(e5 * rinv),
                     (float)(e6 * rinv), (float)(e7 * rinv) };
        *reinterpret_cast<f32x4*>(&rp[lane * 4])       = o0;
        *reinterpret_cast<f32x4*>(&rp[256 + lane * 4]) = o1;
    }
}

// ---------------- Kernel D: readout, pipelined ----------------
// 128x128 tiles, 256 thr = 4 waves (2x2), wave 64c x 64n.
// A (memT bf16) via global_load_lds: linear per-wave LDS dest + inverse-SWZ source.
// B (attn f32->bf16) reg-staged issue-early/write-late, SWZ-scattered writes.
__global__ __launch_bounds__(256, 3) void readout_kernel(const short* __restrict__ memT_bf,
                                                         const float* __restrict__ attn,
                                                         float* __restrict__ out) {
    __shared__ short At[2][4096];   // [buf][swz(c-row,m)] 16 KB
    __shared__ short Bt[2][4096];   // [buf][swz(n-row,m)] 16 KB
    const int t = threadIdx.x;
    const int d  = blockIdx.x;              // 0..1535
    const int xs = d & 7;
    const int hi = d >> 3;                  // 0..191
    const int c0idx  = hi % 6;
    const int rowmid = hi / 6;              // 0..31
    const int rb     = xs | (rowmid << 3);  // 0..255
    const int c0     = c0idx * 128;
    const int rowblk = rb * 128;
    const int b  = rowblk >> 10;
    const int nb = rowblk & 1023;
    const int lane = t & 63, wv = t >> 6;
    const int wcr = wv >> 1, wcc = wv & 1;
    const int lrow = lane & 15, gk = lane >> 4;

    f32x4 acc[4][4];
    #pragma unroll
    for (int fc = 0; fc < 4; ++fc)
        #pragma unroll
        for (int fn = 0; fn < 4; ++fn) acc[fc][fn] = (f32x4){0.f, 0.f, 0.f, 0.f};

    // A DMA inverse-swizzle source coords. Half i: lane data lands at flat short
    // idx 8u, u = i*256 + t (per-wave dest base wv*512 + i*2048; lane*16B by HW).
    int ar[2], ak[2];
    #pragma unroll
    for (int i = 0; i < 2; ++i) {
        int u = i * 256 + t;
        int r0 = ((u >> 2) ^ (u >> 4)) & 1;
        ar[i] = ((u >> 3) << 1) | r0;
        ak[i] = ((u & 3) ^ ((((u >> 3) & 1) << 1) | r0)) << 3;
    }
    // B staging coords: thread covers attn row sr, m-chunk ko (16 elems)
    const int sr = t >> 1;
    const int ko = (t & 1) * 16;
    const float* attnB = attn + (size_t)(rowblk + sr) * MM + ko;

    #define RSWZ(row_, k_) ((((row_) << 5) + (k_)) ^ (((row_) & 7) << 3))

    #define DMA_A(bb_, m0_)                                                    \
        do {                                                                   \
            __builtin_amdgcn_global_load_lds(                                  \
                (const __attribute__((address_space(1))) void*)                \
                    (memT_bf + (size_t)(c0 + ar[0]) * MM + (m0_) + ak[0]),     \
                (__attribute__((address_space(3))) void*)(&At[bb_][wv * 512]), \
                16, 0, 0);                                                     \
            __builtin_amdgcn_global_load_lds(                                  \
                (const __attribute__((address_space(1))) void*)                \
                    (memT_bf + (size_t)(c0 + ar[1]) * MM + (m0_) + ak[1]),     \
                (__attribute__((address_space(3))) void*)(&At[bb_][2048 + wv * 512]), \
                16, 0, 0);                                                     \
        } while (0)

    #define LOAD_B(m0_, v_)                                                    \
        do {                                                                   \
            const f32x4* src = reinterpret_cast<const f32x4*>(attnB + (m0_));  \
            v_[0] = src[0]; v_[1] = src[1]; v_[2] = src[2]; v_[3] = src[3];    \
        } while (0)

    #define WRITE_B(bb_, v_)                                                   \
        do {                                                                   \
            short8 s0 = { f2bf(v_[0][0]), f2bf(v_[0][1]), f2bf(v_[0][2]), f2bf(v_[0][3]), \
                          f2bf(v_[1][0]), f2bf(v_[1][1]), f2bf(v_[1][2]), f2bf(v_[1][3]) }; \
            short8 s1 = { f2bf(v_[2][0]), f2bf(v_[2][1]), f2bf(v_[2][2]), f2bf(v_[2][3]), \
                          f2bf(v_[3][0]), f2bf(v_[3][1]), f2bf(v_[3][2]), f2bf(v_[3][3]) }; \
            *reinterpret_cast<short8*>(&Bt[bb_][RSWZ(sr, ko)])     = s0;       \
            *reinterpret_cast<short8*>(&Bt[bb_][RSWZ(sr, ko + 8)]) = s1;       \
        } while (0)

    #define MFMA_STEP(bb_)                                                     \
        do {                                                                   \
            short8 af[4], bf[4];                                               \
            _Pragma("unroll")                                                  \
            for (int fc = 0; fc < 4; ++fc)                                     \
                af[fc] = *reinterpret_cast<const short8*>(                     \
                    &At[bb_][RSWZ(wcr * 64 + fc * 16 + lrow, gk * 8)]);        \
            _Pragma("unroll")                                                  \
            for (int fn = 0; fn < 4; ++fn)                                     \
                bf[fn] = *reinterpret_cast<const short8*>(                     \
                    &Bt[bb_][RSWZ(wcc * 64 + fn * 16 + lrow, gk * 8)]);        \
            _Pragma("unroll")                                                  \
            for (int fc = 0; fc < 4; ++fc)                                     \
                _Pragma("unroll")                                              \
                for (int fn = 0; fn < 4; ++fn)                                 \
                    acc[fc][fn] = __builtin_amdgcn_mfma_f32_16x16x32_bf16(     \
                        af[fc], bf[fn], acc[fc][fn], 0, 0, 0);                 \
        } while (0)

    {   // prologue: stage m0=0 into buf0
        f32x4 v[4];
        DMA_A(0, 0);
        LOAD_B(0, v);
        WRITE_B(0, v);
    }
    __syncthreads();

    #pragma unroll 1
    for (int step = 0; step < 16; ++step) {
        const int cur = step & 1;
        f32x4 v[4];
        if (step < 15) {
            DMA_A(cur ^ 1, (step + 1) * 32);
            LOAD_B((step + 1) * 32, v);
        }
        MFMA_STEP(cur);
        if (step < 15) WRITE_B(cur ^ 1, v);
        __syncthreads();   // drains DMA vmcnt + ds writes
    }
    #undef DMA_A
    #undef LOAD_B
    #undef WRITE_B
    #undef MFMA_STEP
    #undef RSWZ

    #pragma unroll
    for (int fc = 0; fc < 4; ++fc)
        #pragma unroll
        for (int fn = 0; fn < 4; ++fn)
            #pragma unroll
            for (int reg = 0; reg < 4; ++reg) {
                int c = c0 + wcr * 64 + fc * 16 + gk * 4 + reg;
                int n = nb + wcc * 64 + fn * 16 + lrow;
                out[(size_t)b * ZSTRIDE + (size_t)c * NN + n] = acc[fc][fn][reg];
            }
}
#undef SWZ

extern "C" void kernel_launch(void* const* d_in, const int* in_sizes, int n_in,
                              void* d_out, int out_size, void* d_ws, size_t ws_size,
                              hipStream_t stream) {
    const float* z      = (const float*)d_in[0];
    const float* memory = (const float*)d_in[1];
    float* out      = (float*)d_out;
    float* out_attn = out + OUT_ATTN_OFF;

    char* wsb = (char*)d_ws;
    _Float16* mem_h   = (_Float16*)wsb;               // 786432 B
    _Float16* mem_L   = (_Float16*)(wsb + 786432);    // 786432 B
    short*    memT_bf = (short*)(wsb + 1572864);      // 786432 B
    double*   zinv_ws = (double*)(wsb + 2359296);     // 262144 B

    prep_mem_kernel<<<512, 256, 0, stream>>>(memory, mem_h, mem_L, memT_bf);
    scores_gemm_kernel<<<1024, 512, 0, stream>>>(z, mem_h, mem_L, out_attn, zinv_ws);
    epilogue_kernel<<<RR / 64, 256, 0, stream>>>(out_attn, zinv_ws);
    readout_kernel<<<1536, 256, 0, stream>>>(memT_bf, out_attn, out);
}